// Round 1
// baseline (5901.181 us; speedup 1.0000x reference)
//
#include <hip/hip_runtime.h>
#include <hip/hip_bf16.h>

#define NATOM 100000
#define MNBR  12
#define FDIM  64
#define BDIM  41
#define C2    128      // 2F
#define KPAD  44       // bond K padded to mult of 4 (16B-aligned float4 rows)
#define EPSBN 1e-5f

// ---- ws layout (float units) ----
#define X_OFF    0L           // x: N*64 f32
#define AY_OFF   6400000L     // a|y: N*256 bf16 (occupies 12.8M floats)
#define S_OFF    19200000L    // nbr_sumed: N*64 f32
#define ST_OFF   25600000L    // stats: 3 layers * 768 floats
#define CRY_OFF  25602304L    // crystal sums: 2000*64
#define CNT_OFF  25730304L    // crystal counts: 2000
#define ZERO_CNT (2304L + 128000L + 2000L)

__device__ __forceinline__ float softplus_f(float v) {
    return fmaxf(v, 0.f) + __logf(1.f + __expf(-fabsf(v)));
}

__global__ void k_zero(float* __restrict__ p, long cnt) {
    long i = (long)blockIdx.x * 256 + threadIdx.x;
    if (i < cnt) p[i] = 0.f;
}

// x = atom_fea @ emb_w + emb_b ; 16 atoms/block, thread=(col c, atom-group ag of 4)
__global__ __launch_bounds__(256)
void k_embed(const float* __restrict__ af, const float* __restrict__ ew,
             const float* __restrict__ eb, float* __restrict__ x) {
    int t = threadIdx.x;
    int c = t & 63, ag = t >> 6;
    long n0 = (long)blockIdx.x * 16 + ag * 4;
    float acc[4] = {0.f, 0.f, 0.f, 0.f};
    for (int k4 = 0; k4 < 23; ++k4) {   // 92 = 4*23
        float w0 = ew[(4 * k4 + 0) * FDIM + c];
        float w1 = ew[(4 * k4 + 1) * FDIM + c];
        float w2 = ew[(4 * k4 + 2) * FDIM + c];
        float w3 = ew[(4 * k4 + 3) * FDIM + c];
#pragma unroll
        for (int a = 0; a < 4; ++a) {
            const float4* ar = (const float4*)(af + (n0 + a) * 92);
            float4 v = ar[k4];
            acc[a] += v.x * w0 + v.y * w1 + v.z * w2 + v.w * w3;
        }
    }
    float b = eb[c];
#pragma unroll
    for (int a = 0; a < 4; ++a) x[(n0 + a) * FDIM + c] = acc[a] + b;
}

// ay[n][0:128] = x@W_self + conv_b ; ay[n][128:256] = x@W_nbr   (bf16 out)
#define LIN_ATOMS 8
__global__ __launch_bounds__(256)
void k_lin(const float* __restrict__ x, const float* __restrict__ cw,
           const float* __restrict__ cb, __hip_bfloat16* __restrict__ ay) {
    int t = threadIdx.x;
    long n0 = (long)blockIdx.x * LIN_ATOMS;
    int cc = t & 127;
    const float* wbase = cw + (t < 128 ? 0 : FDIM * C2);
    float acc[LIN_ATOMS];
#pragma unroll
    for (int a = 0; a < LIN_ATOMS; ++a) acc[a] = 0.f;
    const float4* xb = (const float4*)(x + n0 * FDIM);
    for (int k4 = 0; k4 < 16; ++k4) {
        float w0 = wbase[(4 * k4 + 0) * C2 + cc];
        float w1 = wbase[(4 * k4 + 1) * C2 + cc];
        float w2 = wbase[(4 * k4 + 2) * C2 + cc];
        float w3 = wbase[(4 * k4 + 3) * C2 + cc];
#pragma unroll
        for (int a = 0; a < LIN_ATOMS; ++a) {
            float4 v = xb[a * 16 + k4];
            acc[a] += v.x * w0 + v.y * w1 + v.z * w2 + v.w * w3;
        }
    }
    float b = (t < 128) ? cb[cc] : 0.f;
#pragma unroll
    for (int a = 0; a < LIN_ATOMS; ++a)
        ay[(n0 + a) * 256 + t] = __float2bfloat16(acc[a] + b);
}

// Edge kernel: z[n,m,:] = a[n] + y[j] + nbr@W_bond. APPLY=0: accumulate BN1 stats.
// APPLY=1: apply BN1, sigmoid*softplus, sum over m -> s, accumulate BN2 stats.
#define CONV_ATOMS 8
template <int APPLY>
__global__ __launch_bounds__(256)
void k_conv(const __hip_bfloat16* __restrict__ ay, const float* __restrict__ nbr,
            const int* __restrict__ idxp, const float* __restrict__ cw,
            const float* __restrict__ sc1, const float* __restrict__ sh1,
            float* __restrict__ bn1_acc, float* __restrict__ sout,
            float* __restrict__ bn2_acc) {
    __shared__ float nbr_s[CONV_ATOMS * MNBR * KPAD];  // 4224 f
    __shared__ int ids_s[CONV_ATOMS * MNBR];           // 96
    __shared__ float part_s[CONV_ATOMS * 4 * 64];      // 2048 f (also stats reduce buf)

    const int t = threadIdx.x;
    const int c = t & 63;
    const int rs = t >> 6;
    const long n0 = (long)blockIdx.x * CONV_ATOMS;

    // bond-weight columns c and 64+c in registers (rows 128..168 of conv_w[i])
    float4 wf[11], wc[11];
#pragma unroll
    for (int kk = 0; kk < 11; ++kk) {
        float a0[4], a1[4];
#pragma unroll
        for (int q = 0; q < 4; ++q) {
            int k = kk * 4 + q;
            a0[q] = (k < BDIM) ? cw[(2 * FDIM + k) * C2 + c] : 0.f;
            a1[q] = (k < BDIM) ? cw[(2 * FDIM + k) * C2 + 64 + c] : 0.f;
        }
        wf[kk] = make_float4(a0[0], a0[1], a0[2], a0[3]);
        wc[kk] = make_float4(a1[0], a1[1], a1[2], a1[3]);
    }

    for (int i = t; i < CONV_ATOMS * MNBR; i += 256) ids_s[i] = idxp[n0 * MNBR + i];
    for (int i = t; i < CONV_ATOMS * MNBR * KPAD; i += 256) {
        int row = i / KPAD, k = i - row * KPAD;
        nbr_s[i] = (k < BDIM) ? nbr[(n0 * MNBR + row) * (long)BDIM + k] : 0.f;
    }
    __syncthreads();

    float sF = 0.f, sF2 = 0.f, sC = 0.f, sC2 = 0.f;
    float scl_f = 0.f, sft_f = 0.f, scl_c = 0.f, sft_c = 0.f;
    if (APPLY) { scl_f = sc1[c]; sft_f = sh1[c]; scl_c = sc1[64 + c]; sft_c = sh1[64 + c]; }

    for (int a = 0; a < CONV_ATOMS; ++a) {
        long n = n0 + a;
        float aF = __bfloat162float(ay[n * 256 + c]);
        float aC = __bfloat162float(ay[n * 256 + 64 + c]);
        float p = 0.f;
#pragma unroll
        for (int mi = 0; mi < 3; ++mi) {
            int m = rs * 3 + mi;
            long j = ids_s[a * MNBR + m];
            float zf = aF + __bfloat162float(ay[j * 256 + 128 + c]);
            float zc = aC + __bfloat162float(ay[j * 256 + 192 + c]);
            const float4* nb4 = (const float4*)&nbr_s[(a * MNBR + m) * KPAD];
#pragma unroll
            for (int kk = 0; kk < 11; ++kk) {
                float4 v = nb4[kk];
                zf += v.x * wf[kk].x + v.y * wf[kk].y + v.z * wf[kk].z + v.w * wf[kk].w;
                zc += v.x * wc[kk].x + v.y * wc[kk].y + v.z * wc[kk].z + v.w * wc[kk].w;
            }
            if (APPLY) {
                float zfh = zf * scl_f + sft_f;
                float zch = zc * scl_c + sft_c;
                float filt = 1.f / (1.f + __expf(-zfh));
                p += filt * softplus_f(zch);
            } else {
                sF += zf; sF2 += zf * zf; sC += zc; sC2 += zc * zc;
            }
        }
        if (APPLY) part_s[(a * 4 + rs) * 64 + c] = p;
    }
    __syncthreads();

    if (APPLY) {
        float bs = 0.f, bq = 0.f;
        for (int a = rs * 2; a < rs * 2 + 2; ++a) {
            float sv = part_s[(a * 4 + 0) * 64 + c] + part_s[(a * 4 + 1) * 64 + c] +
                       part_s[(a * 4 + 2) * 64 + c] + part_s[(a * 4 + 3) * 64 + c];
            sout[(n0 + a) * FDIM + c] = sv;
            bs += sv; bq += sv * sv;
        }
        atomicAdd(&bn2_acc[c], bs);
        atomicAdd(&bn2_acc[64 + c], bq);
    } else {
        float* red = part_s;
        red[t] = sF; __syncthreads();
        if (t < 64) { float v = red[t] + red[64 + t] + red[128 + t] + red[192 + t]; atomicAdd(&bn1_acc[t], v); }
        __syncthreads();
        red[t] = sC; __syncthreads();
        if (t < 64) { float v = red[t] + red[64 + t] + red[128 + t] + red[192 + t]; atomicAdd(&bn1_acc[64 + t], v); }
        __syncthreads();
        red[t] = sF2; __syncthreads();
        if (t < 64) { float v = red[t] + red[64 + t] + red[128 + t] + red[192 + t]; atomicAdd(&bn1_acc[128 + t], v); }
        __syncthreads();
        red[t] = sC2; __syncthreads();
        if (t < 64) { float v = red[t] + red[64 + t] + red[128 + t] + red[192 + t]; atomicAdd(&bn1_acc[192 + t], v); }
    }
}

// scale/shift from accumulated sums: acc[0:ncols]=sum, acc[ncols:2*ncols]=sumsq
__global__ void k_bnfin(const float* __restrict__ acc, const float* __restrict__ gamma,
                        const float* __restrict__ beta, float* __restrict__ scale,
                        float* __restrict__ shift, float inv_cnt, int ncols) {
    int cidx = threadIdx.x;
    if (cidx < ncols) {
        float mu = acc[cidx] * inv_cnt;
        float ex2 = acc[ncols + cidx] * inv_cnt;
        float var = fmaxf(ex2 - mu * mu, 0.f);
        float s = gamma[cidx] * rsqrtf(var + EPSBN);
        scale[cidx] = s;
        shift[cidx] = beta[cidx] - mu * s;
    }
}

// x = softplus(x + bn2(s))
__global__ void k_x(float* __restrict__ x, const float* __restrict__ s,
                    const float* __restrict__ scale2, const float* __restrict__ shift2) {
    long i = (long)blockIdx.x * 256 + threadIdx.x;
    if (i >= (long)NATOM * FDIM) return;
    int c = (int)(i & 63);
    x[i] = softplus_f(x[i] + s[i] * scale2[c] + shift2[c]);
}

__global__ void k_pool(const float* __restrict__ x, const int* __restrict__ seg,
                       float* __restrict__ cry, float* __restrict__ cnt) {
    long i = (long)blockIdx.x * 256 + threadIdx.x;
    if (i >= (long)NATOM * FDIM) return;
    int n = (int)(i >> 6), c = (int)(i & 63);
    int cr = seg[n];
    atomicAdd(&cry[(long)cr * FDIM + c], x[i]);
    if (c == 0) atomicAdd(&cnt[cr], 1.f);
}

// per-crystal fused MLP head: mean -> fc+relu -> head -> out
__global__ __launch_bounds__(256)
void k_head(const float* __restrict__ cry, const float* __restrict__ cnt,
            const float* __restrict__ fw, const float* __restrict__ fb,
            const float* __restrict__ hw, const float* __restrict__ hb,
            const float* __restrict__ ow, const float* __restrict__ ob,
            float* __restrict__ out) {
    __shared__ float cs[64], h1[128], red[256];
    int t = threadIdx.x, cr = blockIdx.x;
    if (t < 64) cs[t] = cry[(long)cr * 64 + t] / fmaxf(cnt[cr], 1.f);
    __syncthreads();
    if (t < 128) {
        float a = fb[t];
        for (int k = 0; k < 64; ++k) a += cs[k] * fw[k * 128 + t];
        h1[t] = fmaxf(a, 0.f);
    }
    __syncthreads();
    float a = hb[t];
    for (int k = 0; k < 128; ++k) a += h1[k] * hw[k * 256 + t];
    red[t] = a * ow[t];
    __syncthreads();
    for (int off = 128; off > 0; off >>= 1) {
        if (t < off) red[t] += red[t + off];
        __syncthreads();
    }
    if (t == 0) out[cr] = red[0] + ob[0];
}

extern "C" void kernel_launch(void* const* d_in, const int* in_sizes, int n_in,
                              void* d_out, int out_size, void* d_ws, size_t ws_size,
                              hipStream_t stream) {
    const float* atom_fea = (const float*)d_in[0];
    const float* nbr_fea  = (const float*)d_in[1];
    const int*   nbr_idx  = (const int*)d_in[2];
    const int*   seg      = (const int*)d_in[3];
    const float* emb_w    = (const float*)d_in[4];
    const float* emb_b    = (const float*)d_in[5];
    const float* conv_w   = (const float*)d_in[6];
    const float* conv_b   = (const float*)d_in[7];
    const float* bn1_g    = (const float*)d_in[8];
    const float* bn1_b    = (const float*)d_in[9];
    const float* bn2_g    = (const float*)d_in[10];
    const float* bn2_b    = (const float*)d_in[11];
    const float* fc_w     = (const float*)d_in[12];
    const float* fc_b     = (const float*)d_in[13];
    const float* head_w   = (const float*)d_in[14];
    const float* head_b   = (const float*)d_in[15];
    const float* out_w    = (const float*)d_in[16];
    const float* out_b    = (const float*)d_in[17];
    float* out = (float*)d_out;

    float* ws = (float*)d_ws;
    float* x = ws + X_OFF;
    __hip_bfloat16* ay = (__hip_bfloat16*)(ws + AY_OFF);
    float* s = ws + S_OFF;
    float* cry = ws + CRY_OFF;
    float* cnt = ws + CNT_OFF;

    k_zero<<<(int)((ZERO_CNT + 255) / 256), 256, 0, stream>>>(ws + ST_OFF, ZERO_CNT);
    k_embed<<<NATOM / 16, 256, 0, stream>>>(atom_fea, emb_w, emb_b, x);

    for (int i = 0; i < 3; ++i) {
        const float* cw = conv_w + (long)i * 169 * C2;
        const float* cb = conv_b + (long)i * C2;
        float* st = ws + ST_OFF + (long)i * 768;
        float* bn1_acc = st;          // 256
        float* scale1  = st + 256;    // 128
        float* shift1  = st + 384;    // 128
        float* bn2_acc = st + 512;    // 128
        float* scale2  = st + 640;    // 64
        float* shift2  = st + 704;    // 64

        k_lin<<<NATOM / LIN_ATOMS, 256, 0, stream>>>(x, cw, cb, ay);
        k_conv<0><<<NATOM / CONV_ATOMS, 256, 0, stream>>>(ay, nbr_fea, nbr_idx, cw,
                                                          nullptr, nullptr, bn1_acc, nullptr, nullptr);
        k_bnfin<<<1, 128, 0, stream>>>(bn1_acc, bn1_g + i * C2, bn1_b + i * C2,
                                       scale1, shift1, 1.f / 1200000.f, 128);
        k_conv<1><<<NATOM / CONV_ATOMS, 256, 0, stream>>>(ay, nbr_fea, nbr_idx, cw,
                                                          scale1, shift1, nullptr, s, bn2_acc);
        k_bnfin<<<1, 128, 0, stream>>>(bn2_acc, bn2_g + i * 64, bn2_b + i * 64,
                                       scale2, shift2, 1e-5f, 64);
        k_x<<<(NATOM * FDIM) / 256, 256, 0, stream>>>(x, s, scale2, shift2);
    }

    k_pool<<<(NATOM * FDIM) / 256, 256, 0, stream>>>(x, seg, cry, cnt);
    k_head<<<2000, 256, 0, stream>>>(cry, cnt, fc_w, fc_b, head_w, head_b, out_w, out_b, out);
}

// Round 2
// 2189.678 us; speedup vs baseline: 2.6950x; 2.6950x over previous
//
#include <hip/hip_runtime.h>
#include <hip/hip_bf16.h>

#define NATOM 100000
#define MNBR  12
#define FDIM  64
#define BDIM  41
#define C2    128
#define EPSBN 1e-5f
#define NEDGE (NATOM * MNBR)   // 1,200,000
#define KP    64               // bond K padded for MFMA (41 -> 64)
#define ZS_LD 132              // z_s row stride (floats): 4-way max conflict, 16B aligned
#define PS_LD 68

typedef __attribute__((ext_vector_type(8))) short bf16x8;
typedef __attribute__((ext_vector_type(8))) unsigned short u16x8;
typedef __attribute__((ext_vector_type(4))) float f32x4;

// ---- ws layout (float units) ----
#define X_OFF    0L            // x: N*64 f32
#define AY_OFF   6400000L      // ay: N*256 bf16 (12.8M float slots)
#define S_OFF    19200000L     // nbr_sumed: N*64 f32
#define NBRB_OFF 25600000L     // nbr bf16 padded: 1.2M*64 bf16 (38.4M float slots)
#define WBT_OFF  64000000L     // W_bond^T bf16: 128*64 (4096 float slots)
#define BN1S_OFF 64004096L     // 64 slots * 256
#define BN2S_OFF 64020480L     // 64 slots * 128
#define SC1_OFF  64028672L     // 128
#define SH1_OFF  64028800L     // 128
#define SC2_OFF  64028928L     // 64
#define SH2_OFF  64028992L     // 64
#define CRY_OFF  64029056L     // 2000*64
#define CNT_OFF  64157056L     // 2000
#define ZERO_OFF BN1S_OFF
#define ZERO_CNT 154960L

__device__ __forceinline__ float bf2f(unsigned short u) {
    return __uint_as_float(((unsigned)u) << 16);
}
__device__ __forceinline__ float softplus_f(float v) {
    return fmaxf(v, 0.f) + __logf(1.f + __expf(-fabsf(v)));
}

__global__ void k_zero(float* __restrict__ p, long cnt) {
    long i = (long)blockIdx.x * 256 + threadIdx.x;
    if (i < cnt) p[i] = 0.f;
}

// nbr_fea f32 [1.2M][41] -> bf16 [1.2M][64] zero-padded
__global__ void k_nbrcvt(const float* __restrict__ nbr, __hip_bfloat16* __restrict__ outb) {
    long i = (long)blockIdx.x * 256 + threadIdx.x;
    if (i >= (long)NEDGE * KP) return;
    long e = i >> 6;
    int k = (int)(i & 63);
    float v = (k < BDIM) ? nbr[e * BDIM + k] : 0.f;
    outb[i] = __float2bfloat16(v);
}

// W_bond^T bf16 [128 cols][64 k]
__global__ void k_wcvt(const float* __restrict__ cw, __hip_bfloat16* __restrict__ wbt) {
    int i = blockIdx.x * 256 + threadIdx.x;   // < 8192
    int c = i >> 6, k = i & 63;
    float v = (k < BDIM) ? cw[(2 * FDIM + k) * C2 + c] : 0.f;
    wbt[i] = __float2bfloat16(v);
}

// x = atom_fea @ emb_w + emb_b
__global__ __launch_bounds__(256)
void k_embed(const float* __restrict__ af, const float* __restrict__ ew,
             const float* __restrict__ eb, float* __restrict__ x) {
    int t = threadIdx.x;
    int c = t & 63, ag = t >> 6;
    long n0 = (long)blockIdx.x * 16 + ag * 4;
    float acc[4] = {0.f, 0.f, 0.f, 0.f};
    for (int k4 = 0; k4 < 23; ++k4) {
        float w0 = ew[(4 * k4 + 0) * FDIM + c];
        float w1 = ew[(4 * k4 + 1) * FDIM + c];
        float w2 = ew[(4 * k4 + 2) * FDIM + c];
        float w3 = ew[(4 * k4 + 3) * FDIM + c];
#pragma unroll
        for (int a = 0; a < 4; ++a) {
            const float4* ar = (const float4*)(af + (n0 + a) * 92);
            float4 v = ar[k4];
            acc[a] += v.x * w0 + v.y * w1 + v.z * w2 + v.w * w3;
        }
    }
    float b = eb[c];
#pragma unroll
    for (int a = 0; a < 4; ++a) x[(n0 + a) * FDIM + c] = acc[a] + b;
}

// ay[n][0:128] = x@W_self + conv_b ; ay[n][128:256] = x@W_nbr   (bf16)
#define LIN_ATOMS 8
__global__ __launch_bounds__(256)
void k_lin(const float* __restrict__ x, const float* __restrict__ cw,
           const float* __restrict__ cb, __hip_bfloat16* __restrict__ ay) {
    int t = threadIdx.x;
    long n0 = (long)blockIdx.x * LIN_ATOMS;
    int cc = t & 127;
    const float* wbase = cw + (t < 128 ? 0 : FDIM * C2);
    float acc[LIN_ATOMS];
#pragma unroll
    for (int a = 0; a < LIN_ATOMS; ++a) acc[a] = 0.f;
    const float4* xb = (const float4*)(x + n0 * FDIM);
    for (int k4 = 0; k4 < 16; ++k4) {
        float w0 = wbase[(4 * k4 + 0) * C2 + cc];
        float w1 = wbase[(4 * k4 + 1) * C2 + cc];
        float w2 = wbase[(4 * k4 + 2) * C2 + cc];
        float w3 = wbase[(4 * k4 + 3) * C2 + cc];
#pragma unroll
        for (int a = 0; a < LIN_ATOMS; ++a) {
            float4 v = xb[a * 16 + k4];
            acc[a] += v.x * w0 + v.y * w1 + v.z * w2 + v.w * w3;
        }
    }
    float b = (t < 128) ? cb[cc] : 0.f;
#pragma unroll
    for (int a = 0; a < LIN_ATOMS; ++a)
        ay[(n0 + a) * 256 + t] = __float2bfloat16(acc[a] + b);
}

// Edge kernel: MFMA bond GEMM + gather-add.
// APPLY=0: accumulate BN1 column stats.  APPLY=1: BN1 apply, sig*softplus, m-sum -> s, BN2 stats.
// Block: 8 atoms = 96 edges, 384 threads (6 waves, one 16-edge MFMA tile each).
template <int APPLY>
__global__ __launch_bounds__(384)
void k_edge(const __hip_bfloat16* __restrict__ ay,
            const __hip_bfloat16* __restrict__ nbrb,
            const __hip_bfloat16* __restrict__ wbt,
            const int* __restrict__ idxp,
            const float* __restrict__ sc1, const float* __restrict__ sh1,
            float* __restrict__ bn1_slots,
            float* __restrict__ sout, float* __restrict__ bn2_slots) {
    __shared__ float z_s[96 * ZS_LD];   // 50688 B
    __shared__ int ids_s[96];
    __shared__ float bn_s[256];

    const int t = threadIdx.x;
    const int w = t >> 6, l = t & 63;
    const int lo = l & 15, hi = l >> 4;
    const long n0 = (long)blockIdx.x * 8;
    const long e0 = n0 * MNBR;

    if (t < 96) ids_s[t] = idxp[e0 + t];
    if (t < 256) bn_s[t] = 0.f;

    // ---- MFMA phase: z_bond tile [16 edges x 128 cols] per wave ----
    {
        const short* Ab = (const short*)(nbrb + (e0 + w * 16 + lo) * KP + hi * 8);
        bf16x8 a0 = *(const bf16x8*)(Ab);
        bf16x8 a1 = *(const bf16x8*)(Ab + 32);
        f32x4 acc[8];
#pragma unroll
        for (int T = 0; T < 8; ++T) {
            const short* Bb = (const short*)(wbt + (T * 16 + lo) * KP + hi * 8);
            bf16x8 b0 = *(const bf16x8*)(Bb);
            bf16x8 b1 = *(const bf16x8*)(Bb + 32);
            f32x4 z4 = {0.f, 0.f, 0.f, 0.f};
            z4 = __builtin_amdgcn_mfma_f32_16x16x32_bf16(a0, b0, z4, 0, 0, 0);
            z4 = __builtin_amdgcn_mfma_f32_16x16x32_bf16(a1, b1, z4, 0, 0, 0);
            acc[T] = z4;
        }
#pragma unroll
        for (int T = 0; T < 8; ++T)
#pragma unroll
            for (int qq = 0; qq < 4; ++qq)
                z_s[(w * 16 + hi * 4 + qq) * ZS_LD + T * 16 + lo] = acc[T][qq];
    }
    __syncthreads();

    // ---- row phase: thread owns (edge e_l, col quarter q): cols q*16+i and 64+q*16+i ----
    const int e_l = t >> 2, q = t & 3;
    const int j = ids_s[e_l];
    const int n_l = e_l / 12;
    const long nrow = (n0 + n_l) * 256;
    const long jrow = (long)j * 256;
    const __hip_bfloat16* an = ay + nrow + q * 16;
    const __hip_bfloat16* yn = ay + jrow + q * 16;
    u16x8 aF0 = *(const u16x8*)(an);
    u16x8 aF1 = *(const u16x8*)(an + 8);
    u16x8 aC0 = *(const u16x8*)(an + 64);
    u16x8 aC1 = *(const u16x8*)(an + 72);
    u16x8 yF0 = *(const u16x8*)(yn + 128);
    u16x8 yF1 = *(const u16x8*)(yn + 136);
    u16x8 yC0 = *(const u16x8*)(yn + 192);
    u16x8 yC1 = *(const u16x8*)(yn + 200);

    float zfv[16], zcv[16];
    {
        float* zr = &z_s[e_l * ZS_LD + q * 16];
#pragma unroll
        for (int u = 0; u < 4; ++u) {
            float4 a = *(const float4*)(zr + 4 * u);
            float4 b = *(const float4*)(zr + 64 + 4 * u);
            zfv[4 * u + 0] = a.x; zfv[4 * u + 1] = a.y; zfv[4 * u + 2] = a.z; zfv[4 * u + 3] = a.w;
            zcv[4 * u + 0] = b.x; zcv[4 * u + 1] = b.y; zcv[4 * u + 2] = b.z; zcv[4 * u + 3] = b.w;
        }
    }
#pragma unroll
    for (int i = 0; i < 8; ++i) {
        zfv[i]     += bf2f(aF0[i]) + bf2f(yF0[i]);
        zfv[8 + i] += bf2f(aF1[i]) + bf2f(yF1[i]);
        zcv[i]     += bf2f(aC0[i]) + bf2f(yC0[i]);
        zcv[8 + i] += bf2f(aC1[i]) + bf2f(yC1[i]);
    }

    if (APPLY == 0) {
        // write back z_full, then column stats
        float* zw = &z_s[e_l * ZS_LD + q * 16];
#pragma unroll
        for (int u = 0; u < 4; ++u) {
            *(float4*)(zw + 4 * u)      = make_float4(zfv[4 * u], zfv[4 * u + 1], zfv[4 * u + 2], zfv[4 * u + 3]);
            *(float4*)(zw + 64 + 4 * u) = make_float4(zcv[4 * u], zcv[4 * u + 1], zcv[4 * u + 2], zcv[4 * u + 3]);
        }
        __syncthreads();
        {
            const int c = t & 127, seg = t >> 7;
            float s1 = 0.f, s2 = 0.f;
            for (int r = 0; r < 32; ++r) {
                float v = z_s[(seg * 32 + r) * ZS_LD + c];
                s1 += v; s2 += v * v;
            }
            atomicAdd(&bn_s[c], s1);
            atomicAdd(&bn_s[128 + c], s2);
        }
        __syncthreads();
        if (t < 256) atomicAdd(&bn1_slots[(blockIdx.x & 63) * 256 + t], bn_s[t]);
    } else {
        float p[16];
#pragma unroll
        for (int i = 0; i < 16; ++i) {
            float zfh = zfv[i] * sc1[q * 16 + i] + sh1[q * 16 + i];
            float zch = zcv[i] * sc1[64 + q * 16 + i] + sh1[64 + q * 16 + i];
            float filt = 1.f / (1.f + __expf(-zfh));
            p[i] = filt * softplus_f(zch);
        }
        __syncthreads();           // all z_s reads done before aliased p_s writes
        float* p_s = z_s;
#pragma unroll
        for (int u = 0; u < 4; ++u)
            *(float4*)&p_s[e_l * PS_LD + q * 16 + 4 * u] =
                make_float4(p[4 * u], p[4 * u + 1], p[4 * u + 2], p[4 * u + 3]);
        __syncthreads();
        {
            const int g = t >> 6, c = t & 63;
            for (int at = g; at < 8; at += 6) {
                float sv = 0.f;
#pragma unroll
                for (int m = 0; m < 12; ++m) sv += p_s[(at * 12 + m) * PS_LD + c];
                sout[(n0 + at) * FDIM + c] = sv;
                atomicAdd(&bn_s[c], sv);
                atomicAdd(&bn_s[64 + c], sv * sv);
            }
        }
        __syncthreads();
        if (t < 128) atomicAdd(&bn2_slots[(blockIdx.x & 63) * 128 + t], bn_s[t]);
    }
}

// reduce 64 slots -> scale/shift; zero slots for next layer
__global__ void k_bnfin(float* __restrict__ slots, const float* __restrict__ gamma,
                        const float* __restrict__ beta, float* __restrict__ scale,
                        float* __restrict__ shift, float inv_cnt, int nc) {
    int c = threadIdx.x;
    if (c >= nc) return;
    float s1 = 0.f, s2 = 0.f;
    for (int s = 0; s < 64; ++s) {
        s1 += slots[s * 2 * nc + c];
        s2 += slots[s * 2 * nc + nc + c];
    }
    for (int s = 0; s < 64; ++s) {
        slots[s * 2 * nc + c] = 0.f;
        slots[s * 2 * nc + nc + c] = 0.f;
    }
    float mu = s1 * inv_cnt;
    float var = fmaxf(s2 * inv_cnt - mu * mu, 0.f);
    float sc = gamma[c] * rsqrtf(var + EPSBN);
    scale[c] = sc;
    shift[c] = beta[c] - mu * sc;
}

// x = softplus(x + bn2(s))
__global__ void k_x(float* __restrict__ x, const float* __restrict__ s,
                    const float* __restrict__ scale2, const float* __restrict__ shift2) {
    long i = (long)blockIdx.x * 256 + threadIdx.x;
    if (i >= (long)NATOM * FDIM) return;
    int c = (int)(i & 63);
    x[i] = softplus_f(x[i] + s[i] * scale2[c] + shift2[c]);
}

__global__ void k_pool(const float* __restrict__ x, const int* __restrict__ seg,
                       float* __restrict__ cry, float* __restrict__ cnt) {
    long i = (long)blockIdx.x * 256 + threadIdx.x;
    if (i >= (long)NATOM * FDIM) return;
    int n = (int)(i >> 6), c = (int)(i & 63);
    int cr = seg[n];
    atomicAdd(&cry[(long)cr * FDIM + c], x[i]);
    if (c == 0) atomicAdd(&cnt[cr], 1.f);
}

__global__ __launch_bounds__(256)
void k_head(const float* __restrict__ cry, const float* __restrict__ cnt,
            const float* __restrict__ fw, const float* __restrict__ fb,
            const float* __restrict__ hw, const float* __restrict__ hb,
            const float* __restrict__ ow, const float* __restrict__ ob,
            float* __restrict__ out) {
    __shared__ float cs[64], h1[128], red[256];
    int t = threadIdx.x, cr = blockIdx.x;
    if (t < 64) cs[t] = cry[(long)cr * 64 + t] / fmaxf(cnt[cr], 1.f);
    __syncthreads();
    if (t < 128) {
        float a = fb[t];
        for (int k = 0; k < 64; ++k) a += cs[k] * fw[k * 128 + t];
        h1[t] = fmaxf(a, 0.f);
    }
    __syncthreads();
    float a = hb[t];
    for (int k = 0; k < 128; ++k) a += h1[k] * hw[k * 256 + t];
    red[t] = a * ow[t];
    __syncthreads();
    for (int off = 128; off > 0; off >>= 1) {
        if (t < off) red[t] += red[t + off];
        __syncthreads();
    }
    if (t == 0) out[cr] = red[0] + ob[0];
}

extern "C" void kernel_launch(void* const* d_in, const int* in_sizes, int n_in,
                              void* d_out, int out_size, void* d_ws, size_t ws_size,
                              hipStream_t stream) {
    const float* atom_fea = (const float*)d_in[0];
    const float* nbr_fea  = (const float*)d_in[1];
    const int*   nbr_idx  = (const int*)d_in[2];
    const int*   seg      = (const int*)d_in[3];
    const float* emb_w    = (const float*)d_in[4];
    const float* emb_b    = (const float*)d_in[5];
    const float* conv_w   = (const float*)d_in[6];
    const float* conv_b   = (const float*)d_in[7];
    const float* bn1_g    = (const float*)d_in[8];
    const float* bn1_b    = (const float*)d_in[9];
    const float* bn2_g    = (const float*)d_in[10];
    const float* bn2_b    = (const float*)d_in[11];
    const float* fc_w     = (const float*)d_in[12];
    const float* fc_b     = (const float*)d_in[13];
    const float* head_w   = (const float*)d_in[14];
    const float* head_b   = (const float*)d_in[15];
    const float* out_w    = (const float*)d_in[16];
    const float* out_b    = (const float*)d_in[17];
    float* out = (float*)d_out;

    float* ws = (float*)d_ws;
    float* x = ws + X_OFF;
    __hip_bfloat16* ay   = (__hip_bfloat16*)(ws + AY_OFF);
    float* s = ws + S_OFF;
    __hip_bfloat16* nbrb = (__hip_bfloat16*)(ws + NBRB_OFF);
    __hip_bfloat16* wbt  = (__hip_bfloat16*)(ws + WBT_OFF);
    float* bn1s = ws + BN1S_OFF;
    float* bn2s = ws + BN2S_OFF;
    float* sc1 = ws + SC1_OFF;
    float* sh1 = ws + SH1_OFF;
    float* sc2 = ws + SC2_OFF;
    float* sh2 = ws + SH2_OFF;
    float* cry = ws + CRY_OFF;
    float* cnt = ws + CNT_OFF;

    k_zero<<<(int)((ZERO_CNT + 255) / 256), 256, 0, stream>>>(ws + ZERO_OFF, ZERO_CNT);
    k_nbrcvt<<<300000, 256, 0, stream>>>(nbr_fea, nbrb);
    k_embed<<<NATOM / 16, 256, 0, stream>>>(atom_fea, emb_w, emb_b, x);

    for (int i = 0; i < 3; ++i) {
        const float* cw = conv_w + (long)i * 169 * C2;
        const float* cb = conv_b + (long)i * C2;
        k_wcvt<<<32, 256, 0, stream>>>(cw, wbt);
        k_lin<<<NATOM / LIN_ATOMS, 256, 0, stream>>>(x, cw, cb, ay);
        k_edge<0><<<NATOM / 8, 384, 0, stream>>>(ay, nbrb, wbt, nbr_idx,
                                                 nullptr, nullptr, bn1s, nullptr, nullptr);
        k_bnfin<<<1, 128, 0, stream>>>(bn1s, bn1_g + i * C2, bn1_b + i * C2,
                                       sc1, sh1, 1.f / 1200000.f, 128);
        k_edge<1><<<NATOM / 8, 384, 0, stream>>>(ay, nbrb, wbt, nbr_idx,
                                                 sc1, sh1, nullptr, s, bn2s);
        k_bnfin<<<1, 64, 0, stream>>>(bn2s, bn2_g + i * 64, bn2_b + i * 64,
                                      sc2, sh2, 1e-5f, 64);
        k_x<<<(NATOM * FDIM) / 256, 256, 0, stream>>>(x, s, sc2, sh2);
    }

    k_pool<<<(NATOM * FDIM) / 256, 256, 0, stream>>>(x, seg, cry, cnt);
    k_head<<<2000, 256, 0, stream>>>(cry, cnt, fc_w, fc_b, head_w, head_b, out_w, out_b, out);
}

// Round 3
// 1667.380 us; speedup vs baseline: 3.5392x; 1.3132x over previous
//
#include <hip/hip_runtime.h>
#include <hip/hip_bf16.h>

#define NATOM 100000
#define MNBR  12
#define FDIM  64
#define BDIM  41
#define C2    128
#define EPSBN 1e-5f
#define NEDGE (NATOM * MNBR)   // 1,200,000
#define KP    64               // bond K padded for MFMA
#define YLD   132              // y_s row stride (bf16): 264B rows -> 8B-aligned, 2-way banks max
#define ALD   132
#define PLD   68               // p_s row stride (f32)

typedef __attribute__((ext_vector_type(8))) short bf16x8;
typedef __attribute__((ext_vector_type(8))) unsigned short u16x8;
typedef __attribute__((ext_vector_type(4))) unsigned short u16x4;
typedef __attribute__((ext_vector_type(4))) float f32x4;

// ---- ws layout (float units) ----
#define X_OFF    0L            // x: N*64 f32
#define A_OFF    6400000L      // a_buf: N*128 bf16 (x@W_self + conv_b)
#define Y_OFF    12800000L     // y_buf: N*128 bf16 (x@W_nbr)
#define S_OFF    19200000L     // nbr_sumed: N*64 f32
#define NBRB_OFF 25600000L     // nbr bf16 padded: 1.2M*64 bf16
#define WBT_OFF  64000000L     // W_bond^T bf16: 128*64
#define BN1S_OFF 64004096L     // 64 slots * 256
#define BN2S_OFF 64020480L     // 64 slots * 128
#define SC1_OFF  64028672L
#define SH1_OFF  64028800L
#define SC2_OFF  64028928L
#define SH2_OFF  64028992L
#define CRY_OFF  64029056L     // 2000*64
#define CNT_OFF  64157056L     // 2000
#define ZERO_OFF BN1S_OFF
#define ZERO_CNT 154960L

__device__ __forceinline__ float bf2f(unsigned short u) {
    return __uint_as_float(((unsigned)u) << 16);
}
__device__ __forceinline__ float softplus_f(float v) {
    return fmaxf(v, 0.f) + __logf(1.f + __expf(-fabsf(v)));
}

__global__ void k_zero(float* __restrict__ p, long cnt) {
    long i = (long)blockIdx.x * 256 + threadIdx.x;
    if (i < cnt) p[i] = 0.f;
}

// nbr_fea f32 [1.2M][41] -> bf16 [1.2M][64] zero-padded
__global__ void k_nbrcvt(const float* __restrict__ nbr, __hip_bfloat16* __restrict__ outb) {
    long i = (long)blockIdx.x * 256 + threadIdx.x;
    if (i >= (long)NEDGE * KP) return;
    long e = i >> 6;
    int k = (int)(i & 63);
    float v = (k < BDIM) ? nbr[e * BDIM + k] : 0.f;
    outb[i] = __float2bfloat16(v);
}

// W_bond^T bf16 [128 cols][64 k]
__global__ void k_wcvt(const float* __restrict__ cw, __hip_bfloat16* __restrict__ wbt) {
    int i = blockIdx.x * 256 + threadIdx.x;   // < 8192
    int c = i >> 6, k = i & 63;
    float v = (k < BDIM) ? cw[(2 * FDIM + k) * C2 + c] : 0.f;
    wbt[i] = __float2bfloat16(v);
}

__global__ __launch_bounds__(256)
void k_embed(const float* __restrict__ af, const float* __restrict__ ew,
             const float* __restrict__ eb, float* __restrict__ x) {
    int t = threadIdx.x;
    int c = t & 63, ag = t >> 6;
    long n0 = (long)blockIdx.x * 16 + ag * 4;
    float acc[4] = {0.f, 0.f, 0.f, 0.f};
    for (int k4 = 0; k4 < 23; ++k4) {
        float w0 = ew[(4 * k4 + 0) * FDIM + c];
        float w1 = ew[(4 * k4 + 1) * FDIM + c];
        float w2 = ew[(4 * k4 + 2) * FDIM + c];
        float w3 = ew[(4 * k4 + 3) * FDIM + c];
#pragma unroll
        for (int a = 0; a < 4; ++a) {
            const float4* ar = (const float4*)(af + (n0 + a) * 92);
            float4 v = ar[k4];
            acc[a] += v.x * w0 + v.y * w1 + v.z * w2 + v.w * w3;
        }
    }
    float b = eb[c];
#pragma unroll
    for (int a = 0; a < 4; ++a) x[(n0 + a) * FDIM + c] = acc[a] + b;
}

// a_buf[n][c] = (x@W_self)[n][c] + conv_b[c] ; y_buf[n][c] = (x@W_nbr)[n][c]
#define LIN_ATOMS 8
__global__ __launch_bounds__(256)
void k_lin(const float* __restrict__ x, const float* __restrict__ cw,
           const float* __restrict__ cb, __hip_bfloat16* __restrict__ abuf,
           __hip_bfloat16* __restrict__ ybuf) {
    int t = threadIdx.x;
    long n0 = (long)blockIdx.x * LIN_ATOMS;
    int cc = t & 127;
    const float* wbase = cw + (t < 128 ? 0 : FDIM * C2);
    float acc[LIN_ATOMS];
#pragma unroll
    for (int a = 0; a < LIN_ATOMS; ++a) acc[a] = 0.f;
    const float4* xb = (const float4*)(x + n0 * FDIM);
    for (int k4 = 0; k4 < 16; ++k4) {
        float w0 = wbase[(4 * k4 + 0) * C2 + cc];
        float w1 = wbase[(4 * k4 + 1) * C2 + cc];
        float w2 = wbase[(4 * k4 + 2) * C2 + cc];
        float w3 = wbase[(4 * k4 + 3) * C2 + cc];
#pragma unroll
        for (int a = 0; a < LIN_ATOMS; ++a) {
            float4 v = xb[a * 16 + k4];
            acc[a] += v.x * w0 + v.y * w1 + v.z * w2 + v.w * w3;
        }
    }
    if (t < 128) {
        float b = cb[cc];
#pragma unroll
        for (int a = 0; a < LIN_ATOMS; ++a)
            abuf[(n0 + a) * C2 + cc] = __float2bfloat16(acc[a] + b);
    } else {
#pragma unroll
        for (int a = 0; a < LIN_ATOMS; ++a)
            ybuf[(n0 + a) * C2 + cc] = __float2bfloat16(acc[a]);
    }
}

// Edge kernel, in-register: 192 threads = 3 waves = 48 edges = 4 atoms.
// MFMA bond GEMM (global A/B) + LDS-staged gather adds; z never round-trips LDS.
// APPLY=0: BN1 column stats via shfl reduce. APPLY=1: BN1 apply + sig*softplus
// in-register, p -> LDS (aliased), m-sum -> sout, BN2 stats.
template <int APPLY>
__global__ __launch_bounds__(192, 5)
void k_edge(const __hip_bfloat16* __restrict__ abuf,
            const __hip_bfloat16* __restrict__ ybuf,
            const __hip_bfloat16* __restrict__ nbrb,
            const __hip_bfloat16* __restrict__ wbt,
            const int* __restrict__ idxp,
            const float* __restrict__ sc1, const float* __restrict__ sh1,
            float* __restrict__ bn1_slots,
            float* __restrict__ sout, float* __restrict__ bn2_slots) {
    __shared__ __align__(16) char ubuf[48 * PLD * 4];   // 13056 B >= 48*YLD*2
    __shared__ __align__(16) short a_s[4 * ALD];
    __shared__ float bn_s[256];
    __shared__ float sc_s[128], sh_s[128];

    short* y_s = (short*)ubuf;   // [48][YLD] bf16
    float* p_s = (float*)ubuf;   // [48][PLD] f32, used after sync

    const int t = threadIdx.x;
    const int w = t >> 6, l = t & 63;
    const int lo = l & 15, hi = l >> 4;
    const long n0 = (long)blockIdx.x * 4;
    const long e0 = n0 * MNBR;   // 48 edges

    for (int o = t; o < 256; o += 192) bn_s[o] = 0.f;
    if (APPLY) {
        if (t < 128) { sc_s[t] = sc1[t]; sh_s[t] = sh1[t]; }
    }
    // stage a rows (4 atoms x 128 bf16)
    if (t < 64) {
        int at = t >> 4, ch = t & 15;
        u16x8 v = *(const u16x8*)((const short*)abuf + (n0 + at) * C2 + ch * 8);
        u16x4* dst = (u16x4*)&a_s[at * ALD + ch * 8];
        u16x4 v0 = {v[0], v[1], v[2], v[3]};
        u16x4 v1 = {v[4], v[5], v[6], v[7]};
        dst[0] = v0; dst[1] = v1;
    }
    // stage y rows (48 edges x 128 bf16), 4 threads/edge
    {
        int e = t >> 2, q = t & 3;
        long j = idxp[e0 + e];
        const short* src = (const short*)ybuf + j * C2;
#pragma unroll
        for (int i = 0; i < 4; ++i) {
            int ch = i * 4 + q;
            u16x8 v = *(const u16x8*)(src + ch * 8);
            u16x4* dst = (u16x4*)&y_s[e * YLD + ch * 8];
            u16x4 v0 = {v[0], v[1], v[2], v[3]};
            u16x4 v1 = {v[4], v[5], v[6], v[7]};
            dst[0] = v0; dst[1] = v1;
        }
    }

    // MFMA phase (independent of LDS) — overlaps staging latency
    f32x4 acc[8];
    {
        const short* Ab = (const short*)nbrb + (e0 + w * 16 + lo) * KP + hi * 8;
        bf16x8 a0 = *(const bf16x8*)(Ab);
        bf16x8 a1 = *(const bf16x8*)(Ab + 32);
#pragma unroll
        for (int T = 0; T < 8; ++T) {
            const short* Bb = (const short*)wbt + (T * 16 + lo) * KP + hi * 8;
            bf16x8 b0 = *(const bf16x8*)(Bb);
            bf16x8 b1 = *(const bf16x8*)(Bb + 32);
            f32x4 z4 = {0.f, 0.f, 0.f, 0.f};
            z4 = __builtin_amdgcn_mfma_f32_16x16x32_bf16(a0, b0, z4, 0, 0, 0);
            acc[T] = __builtin_amdgcn_mfma_f32_16x16x32_bf16(a1, b1, z4, 0, 0, 0);
        }
    }
    __syncthreads();

    // gather-add: z[e][c] += a[n(e)][c] + y[j(e)][c], fragment layout
    const int ebase = w * 16 + hi * 4;
#pragma unroll
    for (int qq = 0; qq < 4; ++qq) {
        const int e = ebase + qq;
        const int n_l = e / 12;
        const short* yr = &y_s[e * YLD + lo];
        const short* ar = &a_s[n_l * ALD + lo];
#pragma unroll
        for (int T = 0; T < 8; ++T)
            acc[T][qq] += bf2f((unsigned short)yr[T * 16]) + bf2f((unsigned short)ar[T * 16]);
    }

    if (APPLY == 0) {
#pragma unroll
        for (int T = 0; T < 8; ++T) {
            float s1 = acc[T][0] + acc[T][1] + acc[T][2] + acc[T][3];
            float s2 = acc[T][0] * acc[T][0] + acc[T][1] * acc[T][1] +
                       acc[T][2] * acc[T][2] + acc[T][3] * acc[T][3];
            s1 += __shfl_xor(s1, 16); s2 += __shfl_xor(s2, 16);
            s1 += __shfl_xor(s1, 32); s2 += __shfl_xor(s2, 32);
            if (hi == 0) {
                atomicAdd(&bn_s[T * 16 + lo], s1);
                atomicAdd(&bn_s[128 + T * 16 + lo], s2);
            }
        }
        __syncthreads();
        for (int o = t; o < 256; o += 192)
            atomicAdd(&bn1_slots[(blockIdx.x & 63) * 256 + o], bn_s[o]);
    } else {
        float pv[4][4];
#pragma unroll
        for (int T = 0; T < 4; ++T) {
            const int c = T * 16 + lo;
            const float s_f = sc_s[c], h_f = sh_s[c];
            const float s_c = sc_s[64 + c], h_c = sh_s[64 + c];
#pragma unroll
            for (int qq = 0; qq < 4; ++qq) {
                float zf = acc[T][qq] * s_f + h_f;
                float zc = acc[T + 4][qq] * s_c + h_c;
                float filt = 1.f / (1.f + __expf(-zf));
                pv[T][qq] = filt * softplus_f(zc);
            }
        }
        __syncthreads();   // all y_s/a_s reads complete before aliasing as p_s
#pragma unroll
        for (int T = 0; T < 4; ++T)
#pragma unroll
            for (int qq = 0; qq < 4; ++qq)
                p_s[(ebase + qq) * PLD + T * 16 + lo] = pv[T][qq];
        __syncthreads();
        for (int o = t; o < 256; o += 192) {
            int at = o >> 6, c = o & 63;
            float sv = 0.f;
#pragma unroll
            for (int m = 0; m < 12; ++m) sv += p_s[(at * 12 + m) * PLD + c];
            sout[(n0 + at) * FDIM + c] = sv;
            atomicAdd(&bn_s[c], sv);
            atomicAdd(&bn_s[64 + c], sv * sv);
        }
        __syncthreads();
        if (t < 128)
            atomicAdd(&bn2_slots[(blockIdx.x & 63) * 128 + t], bn_s[t]);
    }
}

// reduce 64 slots -> scale/shift; zero slots for next layer
__global__ void k_bnfin(float* __restrict__ slots, const float* __restrict__ gamma,
                        const float* __restrict__ beta, float* __restrict__ scale,
                        float* __restrict__ shift, float inv_cnt, int nc) {
    int c = threadIdx.x;
    if (c >= nc) return;
    float s1 = 0.f, s2 = 0.f;
    for (int s = 0; s < 64; ++s) {
        s1 += slots[s * 2 * nc + c];
        s2 += slots[s * 2 * nc + nc + c];
    }
    for (int s = 0; s < 64; ++s) {
        slots[s * 2 * nc + c] = 0.f;
        slots[s * 2 * nc + nc + c] = 0.f;
    }
    float mu = s1 * inv_cnt;
    float var = fmaxf(s2 * inv_cnt - mu * mu, 0.f);
    float sc = gamma[c] * rsqrtf(var + EPSBN);
    scale[c] = sc;
    shift[c] = beta[c] - mu * sc;
}

__global__ void k_x(float* __restrict__ x, const float* __restrict__ s,
                    const float* __restrict__ scale2, const float* __restrict__ shift2) {
    long i = (long)blockIdx.x * 256 + threadIdx.x;
    if (i >= (long)NATOM * FDIM) return;
    int c = (int)(i & 63);
    x[i] = softplus_f(x[i] + s[i] * scale2[c] + shift2[c]);
}

__global__ void k_pool(const float* __restrict__ x, const int* __restrict__ seg,
                       float* __restrict__ cry, float* __restrict__ cnt) {
    long i = (long)blockIdx.x * 256 + threadIdx.x;
    if (i >= (long)NATOM * FDIM) return;
    int n = (int)(i >> 6), c = (int)(i & 63);
    int cr = seg[n];
    atomicAdd(&cry[(long)cr * FDIM + c], x[i]);
    if (c == 0) atomicAdd(&cnt[cr], 1.f);
}

__global__ __launch_bounds__(256)
void k_head(const float* __restrict__ cry, const float* __restrict__ cnt,
            const float* __restrict__ fw, const float* __restrict__ fb,
            const float* __restrict__ hw, const float* __restrict__ hb,
            const float* __restrict__ ow, const float* __restrict__ ob,
            float* __restrict__ out) {
    __shared__ float cs[64], h1[128], red[256];
    int t = threadIdx.x, cr = blockIdx.x;
    if (t < 64) cs[t] = cry[(long)cr * 64 + t] / fmaxf(cnt[cr], 1.f);
    __syncthreads();
    if (t < 128) {
        float a = fb[t];
        for (int k = 0; k < 64; ++k) a += cs[k] * fw[k * 128 + t];
        h1[t] = fmaxf(a, 0.f);
    }
    __syncthreads();
    float a = hb[t];
    for (int k = 0; k < 128; ++k) a += h1[k] * hw[k * 256 + t];
    red[t] = a * ow[t];
    __syncthreads();
    for (int off = 128; off > 0; off >>= 1) {
        if (t < off) red[t] += red[t + off];
        __syncthreads();
    }
    if (t == 0) out[cr] = red[0] + ob[0];
}

extern "C" void kernel_launch(void* const* d_in, const int* in_sizes, int n_in,
                              void* d_out, int out_size, void* d_ws, size_t ws_size,
                              hipStream_t stream) {
    const float* atom_fea = (const float*)d_in[0];
    const float* nbr_fea  = (const float*)d_in[1];
    const int*   nbr_idx  = (const int*)d_in[2];
    const int*   seg      = (const int*)d_in[3];
    const float* emb_w    = (const float*)d_in[4];
    const float* emb_b    = (const float*)d_in[5];
    const float* conv_w   = (const float*)d_in[6];
    const float* conv_b   = (const float*)d_in[7];
    const float* bn1_g    = (const float*)d_in[8];
    const float* bn1_b    = (const float*)d_in[9];
    const float* bn2_g    = (const float*)d_in[10];
    const float* bn2_b    = (const float*)d_in[11];
    const float* fc_w     = (const float*)d_in[12];
    const float* fc_b     = (const float*)d_in[13];
    const float* head_w   = (const float*)d_in[14];
    const float* head_b   = (const float*)d_in[15];
    const float* out_w    = (const float*)d_in[16];
    const float* out_b    = (const float*)d_in[17];
    float* out = (float*)d_out;

    float* ws = (float*)d_ws;
    float* x = ws + X_OFF;
    __hip_bfloat16* abuf = (__hip_bfloat16*)(ws + A_OFF);
    __hip_bfloat16* ybuf = (__hip_bfloat16*)(ws + Y_OFF);
    float* s = ws + S_OFF;
    __hip_bfloat16* nbrb = (__hip_bfloat16*)(ws + NBRB_OFF);
    __hip_bfloat16* wbt  = (__hip_bfloat16*)(ws + WBT_OFF);
    float* bn1s = ws + BN1S_OFF;
    float* bn2s = ws + BN2S_OFF;
    float* sc1 = ws + SC1_OFF;
    float* sh1 = ws + SH1_OFF;
    float* sc2 = ws + SC2_OFF;
    float* sh2 = ws + SH2_OFF;
    float* cry = ws + CRY_OFF;
    float* cnt = ws + CNT_OFF;

    k_zero<<<(int)((ZERO_CNT + 255) / 256), 256, 0, stream>>>(ws + ZERO_OFF, ZERO_CNT);
    k_nbrcvt<<<300000, 256, 0, stream>>>(nbr_fea, nbrb);
    k_embed<<<NATOM / 16, 256, 0, stream>>>(atom_fea, emb_w, emb_b, x);

    for (int i = 0; i < 3; ++i) {
        const float* cw = conv_w + (long)i * 169 * C2;
        const float* cb = conv_b + (long)i * C2;
        k_wcvt<<<32, 256, 0, stream>>>(cw, wbt);
        k_lin<<<NATOM / LIN_ATOMS, 256, 0, stream>>>(x, cw, cb, abuf, ybuf);
        k_edge<0><<<NATOM / 4, 192, 0, stream>>>(abuf, ybuf, nbrb, wbt, nbr_idx,
                                                 nullptr, nullptr, bn1s, nullptr, nullptr);
        k_bnfin<<<1, 128, 0, stream>>>(bn1s, bn1_g + i * C2, bn1_b + i * C2,
                                       sc1, sh1, 1.f / 1200000.f, 128);
        k_edge<1><<<NATOM / 4, 192, 0, stream>>>(abuf, ybuf, nbrb, wbt, nbr_idx,
                                                 sc1, sh1, nullptr, s, bn2s);
        k_bnfin<<<1, 64, 0, stream>>>(bn2s, bn2_g + i * 64, bn2_b + i * 64,
                                      sc2, sh2, 1e-5f, 64);
        k_x<<<(NATOM * FDIM) / 256, 256, 0, stream>>>(x, s, sc2, sh2);
    }

    k_pool<<<(NATOM * FDIM) / 256, 256, 0, stream>>>(x, seg, cry, cnt);
    k_head<<<2000, 256, 0, stream>>>(cry, cnt, fc_w, fc_b, head_w, head_b, out_w, out_b, out);
}